// Round 1
// baseline (508.321 us; speedup 1.0000x reference)
//
#include <hip/hip_runtime.h>
#include <cfloat>

constexpr int kN = 131072;
constexpr int kC = 128;
constexpr int kRows = 8;   // rows per block (was 16): LDS 36.3KB -> 18.1KB => 8 blocks/CU

__device__ __forceinline__ unsigned fmap(float f) {
    unsigned b = __float_as_uint(f);
    return (b & 0x80000000u) ? ~b : (b | 0x80000000u);
}

__global__ __launch_bounds__(256, 8) void margins_kernel(
    const float* __restrict__ p0, const float* __restrict__ p1,
    const float* __restrict__ p2, const float* __restrict__ p3,
    const float* __restrict__ p4, const float* __restrict__ p5,
    const float* __restrict__ p6, const float* __restrict__ p7,
    const int* __restrict__ targets, float* __restrict__ out,
    unsigned* __restrict__ gmax_ws)
{
    // pitch 34 float2 per row: 272 B row stride (16B aligned), breaks pow2 banks
    __shared__ float2 P2[8][kRows][34];    // [pred][row][chunk] (m1,m2) partials  (17.4 KB)
    __shared__ float tvbuf[8][kRows + 1];  // target value per (pred,row)
    __shared__ float marg[kRows][12];      // margins, pitch 12 (48 B, 16B aligned)
    __shared__ unsigned blockmax;

    const int t = threadIdx.x;
    const int row0 = blockIdx.x * kRows;
    if (t == 0) blockmax = 0u;

    const float* preds[8] = {p0, p1, p2, p3, p4, p5, p6, p7};

    // ---- stage 1: 8 rows x 128 cols x 8 preds, one float4 per (thread,pred) ----
    const int c = t & 31;        // chunk (float4 index within row)
    const int a = t >> 5;        // row within tile, 0..7
    const int row = row0 + a;
    const int tgt = targets[row];
    const size_t off = (size_t)row * kC + c * 4;

    float4 v[8];
#pragma unroll
    for (int j = 0; j < 8; ++j) v[j] = *(const float4*)(preds[j] + off);

    const bool hasT = (tgt >> 2) == c;
    const int  ts   = tgt & 3;

#pragma unroll
    for (int j = 0; j < 8; ++j) {
        const float4 w = v[j];
        float a1 = fmaxf(w.x, w.y), a2 = fminf(w.x, w.y);
        float b1 = fmaxf(w.z, w.w), b2 = fminf(w.z, w.w);
        float m1 = fmaxf(a1, b1);
        float m2 = fmaxf(fminf(a1, b1), fmaxf(a2, b2));
        P2[j][a][c] = make_float2(m1, m2);
        if (hasT) {
            tvbuf[j][a] = (ts == 0) ? w.x : (ts == 1) ? w.y : (ts == 2) ? w.z : w.w;
        }
    }
    __syncthreads();

    // ---- stage 2: all 256 threads; thread = (unit u = pred*8+row, quarter q) ----
    {
        const int u = t >> 2;    // 0..63
        const int q = t & 3;     // quarter of the 16 float4 per unit
        const int j = u >> 3;    // pred
        const int r = u & 7;     // row
        const float4* pr = (const float4*)(&P2[j][r][0]) + q * 4;
        float m1 = -FLT_MAX, m2 = -FLT_MAX;
#pragma unroll
        for (int k = 0; k < 4; ++k) {   // 4 x float4 = 8 (m1,m2) pairs
            const float4 qd = pr[k];
            float lo = fminf(m1, qd.x);
            m1 = fmaxf(m1, qd.x);
            m2 = fmaxf(fmaxf(m2, qd.y), lo);
            lo = fminf(m1, qd.z);
            m1 = fmaxf(m1, qd.z);
            m2 = fmaxf(fmaxf(m2, qd.w), lo);
        }
        // combine the 4 quarters (adjacent lanes) via shuffle
#pragma unroll
        for (int mask = 1; mask <= 2; mask <<= 1) {
            const float o1 = __shfl_xor(m1, mask);
            const float o2 = __shfl_xor(m2, mask);
            const float lo = fminf(m1, o1);
            m1 = fmaxf(m1, o1);
            m2 = fmaxf(fmaxf(m2, o2), lo);
        }
        if (q == 0) {
            const float tv = tvbuf[j][r];
            marg[r][j] = (tv == m1) ? (m1 - m2) : 0.0f;
        }
        // global-max candidate: preds 0..6 only; wave shuffle-max, 1 LDS atomic/wave
        unsigned mv = (j < 7) ? fmap(m1) : 0u;
#pragma unroll
        for (int mask = 4; mask <= 32; mask <<= 1) {
            const unsigned o = __shfl_xor(mv, mask);
            mv = (o > mv) ? o : mv;
        }
        if ((t & 63) == 0) atomicMax(&blockmax, mv);
    }
    __syncthreads();

    // ---- stage 3: softmax over 8 margins per row; coalesced scalar stores ----
    if (t < 64) {
        const int r  = t >> 3;
        const int jj = t & 7;
        const float4 ma = *(const float4*)&marg[r][0];
        const float4 mb = *(const float4*)&marg[r][4];
        float mm = fmaxf(fmaxf(fmaxf(ma.x, ma.y), fmaxf(ma.z, ma.w)),
                         fmaxf(fmaxf(mb.x, mb.y), fmaxf(mb.z, mb.w)));
        const float e0 = __expf((ma.x - mm) * 0.5f);
        const float e1 = __expf((ma.y - mm) * 0.5f);
        const float e2 = __expf((ma.z - mm) * 0.5f);
        const float e3 = __expf((ma.w - mm) * 0.5f);
        const float e4 = __expf((mb.x - mm) * 0.5f);
        const float e5 = __expf((mb.y - mm) * 0.5f);
        const float e6 = __expf((mb.z - mm) * 0.5f);
        const float e7 = __expf((mb.w - mm) * 0.5f);
        const float s  = e0 + e1 + e2 + e3 + e4 + e5 + e6 + e7;
        float num = (jj == 0) ? e0 : (jj == 1) ? e1 : (jj == 2) ? e2 :
                    (jj == 3) ? e3 : (jj == 4) ? e4 : (jj == 5) ? e5 :
                    (jj == 6) ? e6 : e7;
        out[1 + (size_t)row0 * 8 + t] = num / s;
    }
    if (t == 0) atomicMax(gmax_ws, blockmax);
}

__global__ void finalize_kernel(const unsigned* __restrict__ gmax_ws,
                                float* __restrict__ out)
{
    unsigned u = *gmax_ws;
    unsigned b = (u & 0x80000000u) ? (u & 0x7FFFFFFFu) : ~u;
    out[0] = __uint_as_float(b);
}

extern "C" void kernel_launch(void* const* d_in, const int* in_sizes, int n_in,
                              void* d_out, int out_size, void* d_ws, size_t ws_size,
                              hipStream_t stream) {
    const float* p0 = (const float*)d_in[0];
    const float* p1 = (const float*)d_in[1];
    const float* p2 = (const float*)d_in[2];
    const float* p3 = (const float*)d_in[3];
    const float* p4 = (const float*)d_in[4];
    const float* p5 = (const float*)d_in[5];
    const float* p6 = (const float*)d_in[6];
    const float* p7 = (const float*)d_in[7];
    const int* targets = (const int*)d_in[8];
    float* out = (float*)d_out;
    unsigned* ws = (unsigned*)d_ws;

    hipMemsetAsync(ws, 0, sizeof(unsigned), stream);

    dim3 grid(kN / kRows), block(256);
    margins_kernel<<<grid, block, 0, stream>>>(p0, p1, p2, p3, p4, p5, p6, p7,
                                               targets, out, ws);
    finalize_kernel<<<1, 1, 0, stream>>>(ws, out);
}

// Round 2
// 474.687 us; speedup vs baseline: 1.0709x; 1.0709x over previous
//
#include <hip/hip_runtime.h>
#include <cfloat>

constexpr int kN = 131072;
constexpr int kC = 128;
constexpr int kIters = 8;
constexpr int kRowsPerIter = 8;                        // 256 threads / 32 lanes per row
constexpr int kRowsPerBlock = kIters * kRowsPerIter;   // 64

__device__ __forceinline__ unsigned fmap(float f) {
    unsigned b = __float_as_uint(f);
    return (b & 0x80000000u) ? ~b : (b | 0x80000000u);
}

// merge two disjoint (top1, top2) pairs
__device__ __forceinline__ void top2_merge(float& m1, float& m2, float o1, float o2) {
    const float lo = fminf(m1, o1);
    m1 = fmaxf(m1, o1);
    m2 = fmaxf(fmaxf(m2, o2), lo);
}

__global__ __launch_bounds__(256, 8) void margins_kernel(
    const float* __restrict__ p0, const float* __restrict__ p1,
    const float* __restrict__ p2, const float* __restrict__ p3,
    const float* __restrict__ p4, const float* __restrict__ p5,
    const float* __restrict__ p6, const float* __restrict__ p7,
    const int* __restrict__ targets, float* __restrict__ out,
    unsigned* __restrict__ gmax_ws)
{
    __shared__ unsigned blockmax;
    const int t = threadIdx.x;
    if (t == 0) blockmax = 0u;
    __syncthreads();

    const float* preds[8] = {p0, p1, p2, p3, p4, p5, p6, p7};

    const int c    = t & 31;   // float4 chunk within row
    const int rown = t >> 5;   // row within iteration tile, 0..7
    float gm = -FLT_MAX;       // running global max over preds 0..6

    for (int it = 0; it < kIters; ++it) {
        const int row = blockIdx.x * kRowsPerBlock + it * kRowsPerIter + rown;
        const int tgt = targets[row];
        const size_t off = (size_t)row * kC + c * 4;

        const int ts   = tgt & 3;
        const int srcl = (t & 32) + (tgt >> 2);   // wave-lane holding the target column

        float marg[8];

        // two bursts of 4 preds: 4 independent 16B loads in flight per burst,
        // sched_barrier prevents the scheduler from sinking loads into the math
#pragma unroll
        for (int h = 0; h < 2; ++h) {
            float4 v[4];
#pragma unroll
            for (int j = 0; j < 4; ++j) v[j] = *(const float4*)(preds[h * 4 + j] + off);
            __builtin_amdgcn_sched_barrier(0);

#pragma unroll
            for (int j = 0; j < 4; ++j) {
                const float4 w = v[j];
                float a1 = fmaxf(w.x, w.y), a2 = fminf(w.x, w.y);
                float b1 = fmaxf(w.z, w.w), b2 = fminf(w.z, w.w);
                float m1 = fmaxf(a1, b1);
                float m2 = fmaxf(fminf(a1, b1), fmaxf(a2, b2));
                float tv = (ts == 0) ? w.x : (ts == 1) ? w.y : (ts == 2) ? w.z : w.w;
                // butterfly top2 across the 32-lane row group
#pragma unroll
                for (int mask = 1; mask <= 16; mask <<= 1) {
                    const float o1 = __shfl_xor(m1, mask);
                    const float o2 = __shfl_xor(m2, mask);
                    top2_merge(m1, m2, o1, o2);
                }
                tv = __shfl(tv, srcl);             // broadcast target logit
                marg[h * 4 + j] = (tv == m1) ? (m1 - m2) : 0.0f;
                if (h * 4 + j < 7) gm = fmaxf(gm, m1);
            }
        }

        // ---- softmax over 8 margins, fully in registers (all lanes redundant) ----
        const float mm = fmaxf(
            fmaxf(fmaxf(marg[0], marg[1]), fmaxf(marg[2], marg[3])),
            fmaxf(fmaxf(marg[4], marg[5]), fmaxf(marg[6], marg[7])));
        const float e0 = __expf((marg[0] - mm) * 0.5f);
        const float e1 = __expf((marg[1] - mm) * 0.5f);
        const float e2 = __expf((marg[2] - mm) * 0.5f);
        const float e3 = __expf((marg[3] - mm) * 0.5f);
        const float e4 = __expf((marg[4] - mm) * 0.5f);
        const float e5 = __expf((marg[5] - mm) * 0.5f);
        const float e6 = __expf((marg[6] - mm) * 0.5f);
        const float e7 = __expf((marg[7] - mm) * 0.5f);
        const float s  = e0 + e1 + e2 + e3 + e4 + e5 + e6 + e7;
        const float num = (c == 0) ? e0 : (c == 1) ? e1 : (c == 2) ? e2 :
                          (c == 3) ? e3 : (c == 4) ? e4 : (c == 5) ? e5 :
                          (c == 6) ? e6 : e7;
        if (c < 8) out[1 + (size_t)row * 8 + c] = num / s;
    }

    // ---- block/global max ----
    gm = fmaxf(gm, __shfl_xor(gm, 32));
    if ((t & 63) == 0) atomicMax(&blockmax, fmap(gm));
    __syncthreads();
    if (t == 0) atomicMax(gmax_ws, blockmax);
}

__global__ void finalize_kernel(const unsigned* __restrict__ gmax_ws,
                                float* __restrict__ out)
{
    unsigned u = *gmax_ws;
    unsigned b = (u & 0x80000000u) ? (u & 0x7FFFFFFFu) : ~u;
    out[0] = __uint_as_float(b);
}

extern "C" void kernel_launch(void* const* d_in, const int* in_sizes, int n_in,
                              void* d_out, int out_size, void* d_ws, size_t ws_size,
                              hipStream_t stream) {
    const float* p0 = (const float*)d_in[0];
    const float* p1 = (const float*)d_in[1];
    const float* p2 = (const float*)d_in[2];
    const float* p3 = (const float*)d_in[3];
    const float* p4 = (const float*)d_in[4];
    const float* p5 = (const float*)d_in[5];
    const float* p6 = (const float*)d_in[6];
    const float* p7 = (const float*)d_in[7];
    const int* targets = (const int*)d_in[8];
    float* out = (float*)d_out;
    unsigned* ws = (unsigned*)d_ws;

    hipMemsetAsync(ws, 0, sizeof(unsigned), stream);

    dim3 grid(kN / kRowsPerBlock), block(256);
    margins_kernel<<<grid, block, 0, stream>>>(p0, p1, p2, p3, p4, p5, p6, p7,
                                               targets, out, ws);
    finalize_kernel<<<1, 1, 0, stream>>>(ws, out);
}

// Round 3
// 440.933 us; speedup vs baseline: 1.1528x; 1.0766x over previous
//
#include <hip/hip_runtime.h>
#include <cfloat>

constexpr int kN = 131072;
constexpr int kC = 128;
constexpr int kRowsPerBlock = 64;   // 4 waves x 16 rows each

__device__ __forceinline__ unsigned fmap(float f) {
    unsigned b = __float_as_uint(f);
    return (b & 0x80000000u) ? ~b : (b | 0x80000000u);
}

// DPP lane-permute move within 16-lane rows (pure VALU, no DS pipe)
template<int CTRL>
__device__ __forceinline__ float dppmov(float x) {
    return __int_as_float(__builtin_amdgcn_update_dpp(
        __float_as_int(x), __float_as_int(x), CTRL, 0xF, 0xF, false));
}

// merge two disjoint (top1, top2) pairs
__device__ __forceinline__ void top2_merge(float& m1, float& m2, float o1, float o2) {
    const float lo = fminf(m1, o1);
    m1 = fmaxf(m1, o1);
    m2 = fmaxf(fmaxf(m2, o2), lo);
}

__global__ __launch_bounds__(256, 8) void margins_kernel(
    const float* __restrict__ p0, const float* __restrict__ p1,
    const float* __restrict__ p2, const float* __restrict__ p3,
    const float* __restrict__ p4, const float* __restrict__ p5,
    const float* __restrict__ p6, const float* __restrict__ p7,
    const int* __restrict__ targets, float* __restrict__ out,
    unsigned* __restrict__ gmax_ws)
{
    __shared__ float marg_lds[kRowsPerBlock][9];   // [local row][pred], pitch 9
    __shared__ unsigned blockmax;

    const int t = threadIdx.x;
    if (t == 0) blockmax = 0u;
    __syncthreads();

    const float* preds[8] = {p0, p1, p2, p3, p4, p5, p6, p7};

    const int l   = t & 63;          // lane in wave
    const int w   = t >> 6;          // wave id, 0..3
    const int myl = l & 15;          // lane within 16-lane row group
    const int rg  = l >> 4;          // row group within wave, 0..3
    const int R0  = blockIdx.x * kRowsPerBlock + w * 16;   // wave's first row

    // lane's byte offset of (row R0+rg, col myl*4), first half of the row
    const size_t base_off = ((size_t)(R0 + rg) * kC + myl * 4) * sizeof(float);

    int tg[4];
#pragma unroll
    for (int it = 0; it < 4; ++it) tg[it] = targets[R0 + it * 4 + rg];

    float gm = -FLT_MAX;

    // double-buffered payload: group g = (pred j = g>>2, iter it = g&3)
    float4 A[2], B[2];
    {
        const char* p = (const char*)preds[0] + base_off;
        A[0] = *(const float4*)p;
        B[0] = *(const float4*)(p + 256);
    }

#pragma unroll
    for (int g = 0; g < 32; ++g) {
        const int j  = g >> 2;
        const int it = g & 3;

        if (g < 31) {   // prefetch next group (pred-major: same array, next rows)
            const int jn  = (g + 1) >> 2;
            const int itn = (g + 1) & 3;
            const char* p = (const char*)preds[jn] + base_off
                          + (size_t)itn * 4 * kC * sizeof(float);
            A[(g + 1) & 1] = *(const float4*)p;
            B[(g + 1) & 1] = *(const float4*)(p + 256);
        }
        __builtin_amdgcn_sched_barrier(0);

        const float4 va = A[g & 1];
        const float4 vb = B[g & 1];

        // ---- target-value candidate (holder lane only) ----
        const int  tt = tg[it];
        const bool mt = (((tt >> 2) & 15) == myl);
        const float4 hv = (tt & 64) ? vb : va;
        const int el = tt & 3;
        float tvc = (el == 0) ? hv.x : (el == 1) ? hv.y : (el == 2) ? hv.z : hv.w;
        tvc = mt ? tvc : -FLT_MAX;

        // ---- in-lane top2 of 8 ----
        float a1 = fmaxf(va.x, va.y), a2 = fminf(va.x, va.y);
        float b1 = fmaxf(va.z, va.w), b2 = fminf(va.z, va.w);
        const float mA1 = fmaxf(a1, b1);
        const float mA2 = fmaxf(fminf(a1, b1), fmaxf(a2, b2));
        a1 = fmaxf(vb.x, vb.y); a2 = fminf(vb.x, vb.y);
        b1 = fmaxf(vb.z, vb.w); b2 = fminf(vb.z, vb.w);
        const float mB1 = fmaxf(a1, b1);
        const float mB2 = fmaxf(fminf(a1, b1), fmaxf(a2, b2));
        float m1 = mA1, m2 = mA2;
        top2_merge(m1, m2, mB1, mB2);

        // ---- 16-lane butterfly, all DPP (VALU pipe) ----
        { const float o1 = dppmov<0xB1>(m1),  o2 = dppmov<0xB1>(m2);  top2_merge(m1, m2, o1, o2); }
        { const float o1 = dppmov<0x4E>(m1),  o2 = dppmov<0x4E>(m2);  top2_merge(m1, m2, o1, o2); }
        { const float o1 = dppmov<0x124>(m1), o2 = dppmov<0x124>(m2); top2_merge(m1, m2, o1, o2); }
        { const float o1 = dppmov<0x128>(m1), o2 = dppmov<0x128>(m2); top2_merge(m1, m2, o1, o2); }

        // ---- broadcast target value via DPP max-reduce ----
        tvc = fmaxf(tvc, dppmov<0xB1>(tvc));
        tvc = fmaxf(tvc, dppmov<0x4E>(tvc));
        tvc = fmaxf(tvc, dppmov<0x124>(tvc));
        tvc = fmaxf(tvc, dppmov<0x128>(tvc));

        const float margin = (tvc == m1) ? (m1 - m2) : 0.0f;
        if (myl == 0) marg_lds[w * 16 + it * 4 + rg][j] = margin;
        if (j < 7) gm = fmaxf(gm, m1);
    }

    // ---- per-wave softmax + contiguous store (512 B per wave) ----
    {
        const int rr = l >> 2;           // row within wave, 0..15
        const int q  = l & 3;            // quarter: stores outputs q*2, q*2+1
        float m[8];
#pragma unroll
        for (int jj = 0; jj < 8; ++jj) m[jj] = marg_lds[w * 16 + rr][jj];
        float mm = m[0];
#pragma unroll
        for (int jj = 1; jj < 8; ++jj) mm = fmaxf(mm, m[jj]);
        float e[8], s = 0.0f;
#pragma unroll
        for (int jj = 0; jj < 8; ++jj) { e[jj] = __expf((m[jj] - mm) * 0.5f); s += e[jj]; }
        const float inv = 1.0f / s;
        const float o0 = ((q == 0) ? e[0] : (q == 1) ? e[2] : (q == 2) ? e[4] : e[6]) * inv;
        const float o1 = ((q == 0) ? e[1] : (q == 1) ? e[3] : (q == 2) ? e[5] : e[7]) * inv;
        const size_t ob = 1 + ((size_t)(blockIdx.x * kRowsPerBlock + w * 16 + rr)) * 8 + q * 2;
        out[ob]     = o0;
        out[ob + 1] = o1;
    }

    // ---- block / global max over preds 0..6 ----
    gm = fmaxf(gm, __shfl_xor(gm, 16));
    gm = fmaxf(gm, __shfl_xor(gm, 32));
    if (l == 0) atomicMax(&blockmax, fmap(gm));
    __syncthreads();
    if (t == 0) atomicMax(gmax_ws, blockmax);
}

__global__ void finalize_kernel(const unsigned* __restrict__ gmax_ws,
                                float* __restrict__ out)
{
    unsigned u = *gmax_ws;
    unsigned b = (u & 0x80000000u) ? (u & 0x7FFFFFFFu) : ~u;
    out[0] = __uint_as_float(b);
}

extern "C" void kernel_launch(void* const* d_in, const int* in_sizes, int n_in,
                              void* d_out, int out_size, void* d_ws, size_t ws_size,
                              hipStream_t stream) {
    const float* p0 = (const float*)d_in[0];
    const float* p1 = (const float*)d_in[1];
    const float* p2 = (const float*)d_in[2];
    const float* p3 = (const float*)d_in[3];
    const float* p4 = (const float*)d_in[4];
    const float* p5 = (const float*)d_in[5];
    const float* p6 = (const float*)d_in[6];
    const float* p7 = (const float*)d_in[7];
    const int* targets = (const int*)d_in[8];
    float* out = (float*)d_out;
    unsigned* ws = (unsigned*)d_ws;

    hipMemsetAsync(ws, 0, sizeof(unsigned), stream);

    dim3 grid(kN / kRowsPerBlock), block(256);
    margins_kernel<<<grid, block, 0, stream>>>(p0, p1, p2, p3, p4, p5, p6, p7,
                                               targets, out, ws);
    finalize_kernel<<<1, 1, 0, stream>>>(ws, out);
}